// Round 1
// baseline (100.551 us; speedup 1.0000x reference)
//
#include <hip/hip_runtime.h>
#include <float.h>
#include <stdint.h>

// Problem: dist[b, tails[e]] += ew[e] where heads[e]==batch[b,0,0] && etype[e]==batch[b,0,2],
// then row-softmax(dist) over N=50000 nodes. B=64, E=1e6.
// Matches are rare (~5 total across all b) -> sparse scatter + dense softmax.

#define SOFTMAX_BLOCK 1024

__device__ __forceinline__ float waveMax(float v) {
#pragma unroll
    for (int off = 32; off; off >>= 1) v = fmaxf(v, __shfl_down(v, off, 64));
    return v;
}
__device__ __forceinline__ float waveSum(float v) {
#pragma unroll
    for (int off = 32; off; off >>= 1) v += __shfl_down(v, off, 64);
    return v;
}

// One thread per edge; batch (h,r) keys staged in LDS (uniform-address reads = broadcast).
__global__ void scatter_kernel(const int* __restrict__ edge_index,  // (2,E) flat: heads then tails
                               const int* __restrict__ etype,       // (E,)
                               const float* __restrict__ ew,        // (E,)
                               const int* __restrict__ batch,       // (B,32,3) flat
                               float* __restrict__ dist,            // (B,N), pre-zeroed
                               int E, int N, int B) {
    extern __shared__ unsigned s_keys[];
    for (int i = threadIdx.x; i < B; i += blockDim.x) {
        unsigned h = (unsigned)batch[i * 96 + 0];   // batch[b,0,0]
        unsigned r = (unsigned)batch[i * 96 + 2];   // batch[b,0,2]
        s_keys[i] = (h << 16) | (r & 0xFFFFu);      // h<50000, r<237 — both fit 16 bits
    }
    __syncthreads();
    int e = blockIdx.x * blockDim.x + threadIdx.x;
    if (e >= E) return;
    unsigned key = ((unsigned)edge_index[e] << 16) | ((unsigned)etype[e] & 0xFFFFu);
    int tail = -1;       // tails are >=0, so -1 is a safe "not loaded yet" sentinel
    float w = 0.0f;
    for (int b = 0; b < B; ++b) {
        if (s_keys[b] == key) {
            if (tail < 0) { tail = edge_index[E + e]; w = ew[e]; }
            atomicAdd(dist + (size_t)b * N + tail, w);   // ~5 atomics total across grid
        }
    }
}

// One block per row. 3 passes: max, sum(exp), write. float4 path when N%4==0.
__global__ __launch_bounds__(SOFTMAX_BLOCK)
void softmax_kernel(float* __restrict__ dist, int N) {
    __shared__ float s_red[SOFTMAX_BLOCK / 64];
    __shared__ float s_bcast;
    const int tid = threadIdx.x;
    const int nw = SOFTMAX_BLOCK / 64;
    float* row = dist + (size_t)blockIdx.x * N;
    const bool vec4 = ((N & 3) == 0) && ((((uintptr_t)row) & 15) == 0);

    // ---- pass 1: row max ----
    float m = -FLT_MAX;
    if (vec4) {
        const float4* row4 = (const float4*)row;
        const int N4 = N >> 2;
        for (int i = tid; i < N4; i += SOFTMAX_BLOCK) {
            float4 v = row4[i];
            m = fmaxf(m, fmaxf(fmaxf(v.x, v.y), fmaxf(v.z, v.w)));
        }
    } else {
        for (int i = tid; i < N; i += SOFTMAX_BLOCK) m = fmaxf(m, row[i]);
    }
    m = waveMax(m);
    if ((tid & 63) == 0) s_red[tid >> 6] = m;
    __syncthreads();
    if (tid < 64) {
        float v = (tid < nw) ? s_red[tid] : -FLT_MAX;
        v = waveMax(v);
        if (tid == 0) s_bcast = v;
    }
    __syncthreads();
    const float M = s_bcast;
    __syncthreads();   // protect s_red/s_bcast reuse below

    // ---- pass 2: sum of exp(x - M) ----
    float s = 0.0f;
    if (vec4) {
        const float4* row4 = (const float4*)row;
        const int N4 = N >> 2;
        for (int i = tid; i < N4; i += SOFTMAX_BLOCK) {
            float4 v = row4[i];
            s += __expf(v.x - M) + __expf(v.y - M) + __expf(v.z - M) + __expf(v.w - M);
        }
    } else {
        for (int i = tid; i < N; i += SOFTMAX_BLOCK) s += __expf(row[i] - M);
    }
    s = waveSum(s);
    if ((tid & 63) == 0) s_red[tid >> 6] = s;
    __syncthreads();
    if (tid < 64) {
        float v = (tid < nw) ? s_red[tid] : 0.0f;
        v = waveSum(v);
        if (tid == 0) s_bcast = v;
    }
    __syncthreads();
    const float invS = 1.0f / s_bcast;

    // ---- pass 3: write exp(x - M) / S (in place) ----
    if (vec4) {
        float4* row4 = (float4*)row;
        const int N4 = N >> 2;
        for (int i = tid; i < N4; i += SOFTMAX_BLOCK) {
            float4 v = row4[i];
            v.x = __expf(v.x - M) * invS;
            v.y = __expf(v.y - M) * invS;
            v.z = __expf(v.z - M) * invS;
            v.w = __expf(v.w - M) * invS;
            row4[i] = v;
        }
    } else {
        for (int i = tid; i < N; i += SOFTMAX_BLOCK) row[i] = __expf(row[i] - M) * invS;
    }
}

extern "C" void kernel_launch(void* const* d_in, const int* in_sizes, int n_in,
                              void* d_out, int out_size, void* d_ws, size_t ws_size,
                              hipStream_t stream) {
    const int*   edge_index = (const int*)d_in[0];   // (2,E)
    const int*   edge_type  = (const int*)d_in[1];   // (E,)
    const int*   batch      = (const int*)d_in[2];   // (B,32,3)
    const float* ew         = (const float*)d_in[3]; // (E,)
    // d_in[4] = num_nodes (device scalar) — derived from host-known sizes instead.

    const int E = in_sizes[1];
    const int B = in_sizes[2] / 96;          // 32*3 per batch row
    const int N = (out_size - 1) / B;        // out = (B,N) softmax + 1 ALPHA scalar

    float* out = (float*)d_out;

    // Zero dist AND the trailing ALPHA slot (ALPHA = 0.0f) in one memset.
    hipMemsetAsync(d_out, 0, (size_t)out_size * sizeof(float), stream);

    const int threads = 256;
    const int blocks = (E + threads - 1) / threads;
    scatter_kernel<<<blocks, threads, B * sizeof(unsigned), stream>>>(
        edge_index, edge_type, ew, batch, out, E, N, B);

    softmax_kernel<<<B, SOFTMAX_BLOCK, 0, stream>>>(out, N);
}